// Round 5
// baseline (269.880 us; speedup 1.0000x reference)
//
#include <hip/hip_runtime.h>
#include <hip/hip_bf16.h>
#include <stdint.h>

#define B_   8
#define S_   4096
#define SP1_ 4097
#define D_   256
#define R_   512
#define C_   2048
#define BS_  32768          // B*S

typedef __attribute__((ext_vector_type(8))) short bf16x8;
typedef __attribute__((ext_vector_type(4))) float f32x4;
typedef unsigned short u16;

__device__ __forceinline__ u16 f2bf(float f) {
  __hip_bfloat16 h = __float2bfloat16(f);
  return *(u16*)&h;
}
__device__ __forceinline__ float bf2f(u16 u) {
  __hip_bfloat16 h = *(__hip_bfloat16*)&u;
  return __bfloat162float(h);
}

// async global->LDS, 16B per lane; LDS dst = wave-uniform base + lane*16
__device__ __forceinline__ void gload16(const u16* g, u16* l) {
  __builtin_amdgcn_global_load_lds(
      (const __attribute__((address_space(1))) uint32_t*)g,
      (__attribute__((address_space(3))) uint32_t*)l, 16, 0, 0);
}

// ======== K1: prep (softmax-per-batch | cast+qsq | transpose_E | zero | cls copy) ========
// Section order puts the 8 long-chain softmax blocks FIRST so they dispatch early and
// hide under the 8192 cast blocks.
#define SMAXB 8
#define NCAST 8192
#define NCB   (SMAXB + NCAST)    // 8200
#define TEB2  (NCB + 1024)       // 9224
#define ZB2   (TEB2 + 33)        // 9257
#define K1GRID (ZB2 + 8)         // 9265

__global__ void k_prep(const float* __restrict__ x, const float* __restrict__ clsw,
                       const float* __restrict__ clsb, const float* __restrict__ E,
                       u16* __restrict__ posb, float* __restrict__ qsq,
                       u16* __restrict__ ET, float* __restrict__ zbase,
                       u16* __restrict__ proj, float* __restrict__ out) {
  __shared__ float sm[33 * 32];               // 1056 floats (softmax uses 1024)
  int blk = blockIdx.x, t = threadIdx.x;
  if (blk < SMAXB) {
    // ---- fused w0 + softmax -> proj for batch b (replaces old k_softmax + w0 section) ----
    int b = blk;
    const float* cls = x + (size_t)b * SP1_ * D_;
    float* w  = sm;                           // w0[512]
    float* bb = sm + 512;                     // clsb[512]
    float a0 = 0.f, a1 = 0.f;
    for (int d = 0; d < D_; d++) {
      float cd = cls[d];
      a0 += cd * clsw[d * R_ + t];
      a1 += cd * clsw[d * R_ + t + 256];
    }
    w[t] = a0; w[t + 256] = a1;
    bb[t] = clsb[t]; bb[t + 256] = clsb[t + 256];
    __syncthreads();
    int wv = t >> 6, lane = t & 63;
    for (int j = 0; j < 64; j++) {            // each wave: 64 of the 256 d-rows
      int d = wv * 64 + j;
      float c = cls[d];
      float l[8];
      #pragma unroll
      for (int k = 0; k < 8; k++) { int r = lane + k * 64; l[k] = c * w[r] + bb[r]; }
      float m = l[0];
      #pragma unroll
      for (int k = 1; k < 8; k++) m = fmaxf(m, l[k]);
      #pragma unroll
      for (int off = 1; off < 64; off <<= 1) m = fmaxf(m, __shfl_xor(m, off));
      float e[8], s = 0.f;
      #pragma unroll
      for (int k = 0; k < 8; k++) { e[k] = expf(l[k] - m); s += e[k]; }
      #pragma unroll
      for (int off = 1; off < 64; off <<= 1) s += __shfl_xor(s, off);
      float inv = 1.0f / s;
      size_t base = ((size_t)b * D_ + d) * R_;
      #pragma unroll
      for (int k = 0; k < 8; k++) proj[base + lane + k * 64] = f2bf(e[k] * inv);
    }
  } else if (blk < NCB) {
    int wv = t >> 6, lane = t & 63;
    int row = (blk - SMAXB) * 4 + wv;
    int b = row >> 12, s = row & 4095;
    const float4 v = *(const float4*)(x + (size_t)b * SP1_ * D_ + (size_t)(s + 1) * D_ + lane * 4);
    ushort4 u;
    u.x = f2bf(v.x); u.y = f2bf(v.y); u.z = f2bf(v.z); u.w = f2bf(v.w);
    *(ushort4*)(posb + (size_t)row * D_ + lane * 4) = u;
    float ss = v.x * v.x + v.y * v.y + v.z * v.z + v.w * v.w;
    #pragma unroll
    for (int off = 1; off < 64; off <<= 1) ss += __shfl_xor(ss, off);
    if (lane == 0) qsq[row] = ss;
  } else if (blk < TEB2) {
    int id = blk - NCB;                       // 0..1023
    int c0 = (id & 63) * 32, r0 = (id >> 6) * 32;
    int tx = t & 31, ty = t >> 5;             // 32 x 8
    float (*tile)[33] = (float(*)[33])sm;
    #pragma unroll
    for (int i = 0; i < 4; i++)
      tile[ty + i * 8][tx] = E[(size_t)(r0 + ty + i * 8) * C_ + c0 + tx];
    __syncthreads();
    #pragma unroll
    for (int i = 0; i < 4; i++)
      ET[(size_t)(c0 + ty + i * 8) * R_ + r0 + tx] = f2bf(tile[tx][ty + i * 8]);
  } else if (blk < ZB2) {
    int id = blk - TEB2;                      // 0..32  (zero esq+hist+acc = 131328 B)
    int o1 = id * 1024 + t;       if (o1 < 32832) ((uint32_t*)zbase)[o1] = 0u;
    int o2 = id * 1024 + 256 + t; if (o2 < 32832) ((uint32_t*)zbase)[o2] = 0u;
    int o3 = id * 1024 + 512 + t; if (o3 < 32832) ((uint32_t*)zbase)[o3] = 0u;
    int o4 = id * 1024 + 768 + t; if (o4 < 32832) ((uint32_t*)zbase)[o4] = 0u;
  } else {
    int b = blk - ZB2;
    size_t xb = (size_t)b * SP1_ * D_;
    if (t < 64) *(float4*)(out + xb + t * 4) = *(const float4*)(x + xb + t * 4);
  }
}

// ================= K3: emb GEMM, 2-phase double-buffered prefetch (unchanged) =================
__global__ __launch_bounds__(256) void k_gemm_emb(const u16* __restrict__ proj,
                                                  const u16* __restrict__ ET,
                                                  u16* __restrict__ embT,
                                                  float* __restrict__ esq) {
  int nt = blockIdx.x, mt = blockIdx.y, b = blockIdx.z;
  int n0 = nt * 128, m0 = mt * 64;
  const u16* A  = proj + (size_t)b * D_ * R_;   // d-rows x R
  const u16* Bt = ET;                           // c-rows x R
  __shared__ u16 tA[2][64 * 64], tB[2][128 * 64];   // 16 KB + 32 KB (dbuf)
  int tid = threadIdx.x;
  int wv = tid >> 6, lane = tid & 63, ln = lane & 15, qd = lane >> 4;
  int srow8 = lane >> 3, sc = lane & 7;
  int gc = sc ^ srow8;                          // fetch chunk so slot sc holds chunk sc^(row&7)
  f32x4 acc[8];
  #pragma unroll
  for (int nf = 0; nf < 8; nf++) acc[nf] = (f32x4){0.f, 0.f, 0.f, 0.f};

#define STAGE_EMB(bufi, kkk) do {                                                   \
    _Pragma("unroll")                                                               \
    for (int i_ = 0; i_ < 2; i_++) {                                                \
      int r0_ = wv * 16 + i_ * 8;                                                   \
      gload16(A + (size_t)(m0 + r0_ + srow8) * R_ + (kkk) + gc * 8,                 \
              &tA[bufi][r0_ * 64]);                                                 \
    }                                                                               \
    _Pragma("unroll")                                                               \
    for (int i_ = 0; i_ < 4; i_++) {                                                \
      int r0_ = wv * 32 + i_ * 8;                                                   \
      gload16(Bt + (size_t)(n0 + r0_ + srow8) * R_ + (kkk) + gc * 8,                \
              &tB[bufi][r0_ * 64]);                                                 \
    }                                                                               \
  } while (0)

  STAGE_EMB(0, 0);
  __syncthreads();
  int cur = 0;
  for (int kk = 0; kk < R_; kk += 64) {
    int nxt = kk + 64;
    if (nxt < R_) STAGE_EMB(cur ^ 1, nxt);
    #pragma unroll
    for (int kc = 0; kc < 2; kc++) {
      int slot = (kc * 4 + qd) ^ (ln & 7);
      bf16x8 af = *(bf16x8*)&tA[cur][(wv * 16 + ln) * 64 + slot * 8];
      bf16x8 bfr[8];
      #pragma unroll
      for (int nf = 0; nf < 8; nf++) bfr[nf] = *(bf16x8*)&tB[cur][(nf * 16 + ln) * 64 + slot * 8];
      #pragma unroll
      for (int nf = 0; nf < 8; nf++)
        acc[nf] = __builtin_amdgcn_mfma_f32_16x16x32_bf16(af, bfr[nf], acc[nf], 0, 0, 0);
    }
    __syncthreads();
    cur ^= 1;
  }
#undef STAGE_EMB
  // epilogue: row d = m0+wv*16+qd*4+reg, col c = n0+nf*16+ln
  #pragma unroll
  for (int nf = 0; nf < 8; nf++) {
    int c = n0 + nf * 16 + ln;
    int dbase = m0 + wv * 16 + qd * 4;
    f32x4 v = acc[nf];
    ushort4 u;
    u.x = f2bf(v[0]); u.y = f2bf(v[1]); u.z = f2bf(v[2]); u.w = f2bf(v[3]);
    *(ushort4*)&embT[((size_t)b * C_ + c) * D_ + dbase] = u;
    float ss = v[0]*v[0] + v[1]*v[1] + v[2]*v[2] + v[3]*v[3];
    ss += __shfl_xor(ss, 16);
    ss += __shfl_xor(ss, 32);
    if (qd == 0) atomicAdd(&esq[b * C_ + c], ss);
  }
}

// ======== K4: dist + argmin + hist + SSE + gather + (last-block) perplexity ========
// Grid (8 b, 64 st) = 512 blocks = 2/CU; linear id%8 = b -> XCD-pinned batch panel.
// 256 thr = 4 waves; all waves share the block's 64 rows (A in regs: areg[4][8]);
// wave wv owns cols wv*16+ln of each 64-col tile -> every staged LDS byte read exactly once.
// Static dbuf tB0/tB1 (alias-analysis-safe, R3-proven). Same XOR-swizzle family:
// LDS slot s of col c holds global chunk s^(c&7); read slot=(kt*4+qd)^(ln&7) -> conflict-free.
__global__ __launch_bounds__(256, 2) void k_dist(const u16* __restrict__ posb,
                                                 const u16* __restrict__ embT,
                                                 const float* __restrict__ esq,
                                                 const float* __restrict__ qsq,
                                                 int* __restrict__ hist,
                                                 float* __restrict__ acc,
                                                 float* __restrict__ out) {
  int b = blockIdx.x, st = blockIdx.y;
  int m0 = st * 64;
  const u16* A  = posb + (size_t)b * S_ * D_;   // S x D
  const u16* Bt = embT + (size_t)b * C_ * D_;   // C x D
  __shared__ u16 tB0[64 * 256];                 // 32 KB
  __shared__ u16 tB1[64 * 256];                 // 32 KB
  __shared__ float sh_esq[2048];                // 8 KB
  __shared__ float pbv[4][64];
  __shared__ int   pbi[4][64];
  __shared__ int   fidx[64];
  __shared__ float smP[8];
  __shared__ int   lastflag;
  int tid = threadIdx.x;
  int wv = tid >> 6, lane = tid & 63, ln = lane & 15, qd = lane >> 4;

  #pragma unroll
  for (int i = 0; i < 2; i++)
    *(float4*)&sh_esq[tid * 8 + i * 4] = *(const float4*)&esq[b * C_ + tid * 8 + i * 4];

  // A rows -> registers (loaded once): lane ln holds row m0+mi*16+ln, chunk qd*8 + tt*32
  bf16x8 areg[4][8];
  #pragma unroll
  for (int mi = 0; mi < 4; mi++) {
    const u16* ar = A + (size_t)(m0 + mi * 16 + ln) * D_ + qd * 8;
    #pragma unroll
    for (int tt = 0; tt < 8; tt++) areg[mi][tt] = *(const bf16x8*)(ar + tt * 32);
  }

  float rbv[4][4]; int rbc[4][4];
  #pragma unroll
  for (int mi = 0; mi < 4; mi++)
    #pragma unroll
    for (int r = 0; r < 4; r++) { rbv[mi][r] = 3.4e38f; rbc[mi][r] = 0; }

  // wave stages its own 16 cols: 8 gload16, each covers 2 cols x 32 chunks
#define STAGE_D(TB, ct) do {                                                        \
    _Pragma("unroll")                                                               \
    for (int i_ = 0; i_ < 8; i_++) {                                                \
      int c0_ = wv * 16 + i_ * 2;                                                   \
      int cl_ = c0_ + (lane >> 5);                                                  \
      int gc_ = (lane & 31) ^ (cl_ & 7);                                            \
      gload16(Bt + (size_t)((ct) * 64 + cl_) * D_ + gc_ * 8, TB + c0_ * 256);       \
    }                                                                               \
  } while (0)

#define COMPUTE_D(TB, ct) do {                                                      \
    f32x4 cacc[4];                                                                  \
    _Pragma("unroll")                                                               \
    for (int mi_ = 0; mi_ < 4; mi_++) cacc[mi_] = (f32x4){0.f, 0.f, 0.f, 0.f};      \
    _Pragma("unroll")                                                               \
    for (int kt_ = 0; kt_ < 8; kt_++) {                                             \
      int slot_ = (kt_ * 4 + qd) ^ (ln & 7);                                        \
      bf16x8 bfr = *(bf16x8*)&TB[(wv * 16 + ln) * 256 + slot_ * 8];                 \
      _Pragma("unroll")                                                             \
      for (int mi_ = 0; mi_ < 4; mi_++)                                             \
        cacc[mi_] = __builtin_amdgcn_mfma_f32_16x16x32_bf16(                        \
            areg[mi_][kt_], bfr, cacc[mi_], 0, 0, 0);                               \
    }                                                                               \
    int c_ = (ct) * 64 + wv * 16 + ln;                                              \
    float e_ = sh_esq[c_];                                                          \
    _Pragma("unroll")                                                               \
    for (int mi_ = 0; mi_ < 4; mi_++)                                               \
      _Pragma("unroll")                                                             \
      for (int r_ = 0; r_ < 4; r_++) {                                              \
        float s_ = e_ - 2.0f * cacc[mi_][r_];                                       \
        if (s_ < rbv[mi_][r_] || (s_ == rbv[mi_][r_] && c_ < rbc[mi_][r_])) {       \
          rbv[mi_][r_] = s_; rbc[mi_][r_] = c_;                                     \
        }                                                                           \
      }                                                                             \
  } while (0)

  STAGE_D(tB0, 0);
  __syncthreads();
  for (int ct = 0; ct < 32; ct += 2) {
    STAGE_D(tB1, ct + 1);                     // async prefetch into the other symbol
    COMPUTE_D(tB0, ct);                       // 8 ds_read + 32 MFMA + argmin hides it
    __syncthreads();
    if (ct + 2 < 32) STAGE_D(tB0, ct + 2);
    COMPUTE_D(tB1, ct + 1);
    __syncthreads();
  }
#undef STAGE_D
#undef COMPUTE_D

  // 16-lane reduce per (mi, r); row = mi*16 + qd*4 + r; waves hold disjoint col sets
  #pragma unroll
  for (int mi = 0; mi < 4; mi++)
    #pragma unroll
    for (int r = 0; r < 4; r++) {
      float bv = rbv[mi][r]; int bc = rbc[mi][r];
      #pragma unroll
      for (int off = 1; off < 16; off <<= 1) {
        float ov = __shfl_xor(bv, off);
        int   oc = __shfl_xor(bc, off);
        if (ov < bv || (ov == bv && oc < bc)) { bv = ov; bc = oc; }
      }
      if (ln == 0) {
        int rl = mi * 16 + qd * 4 + r;        // 0..63
        pbv[wv][rl] = bv;
        pbi[wv][rl] = bc;
      }
    }
  __syncthreads();
  // combine the 4 waves' column sets (index tie-break, order-independent), hist, SSE
  if (tid < 64) {
    float fv = pbv[0][tid]; int fi = pbi[0][tid];
    #pragma unroll
    for (int w = 1; w < 4; w++) {
      float v = pbv[w][tid]; int ix = pbi[w][tid];
      if (v < fv || (v == fv && ix < fi)) { fv = v; fi = ix; }
    }
    fidx[tid] = fi;
    atomicAdd(&hist[b * C_ + fi], 1);
    float sse = fv + qsq[b * S_ + m0 + tid];
    #pragma unroll
    for (int off = 1; off < 64; off <<= 1) sse += __shfl_xor(sse, off);
    if (tid == 0) atomicAdd(&acc[0], sse);
  }
  __syncthreads();
  // gather + write out (wave wv owns rows wv*16..+15)
  size_t xb = (size_t)b * SP1_ * D_;
  #pragma unroll
  for (int j = 0; j < 16; j++) {
    int r = wv * 16 + j;
    int ix = fidx[r];
    int s = m0 + r;
    ushort4 q4 = *(const ushort4*)(Bt + (size_t)ix * D_ + lane * 4);
    float4 q;
    q.x = bf2f(q4.x); q.y = bf2f(q4.y); q.z = bf2f(q4.z); q.w = bf2f(q4.w);
    *(float4*)(out + xb + (size_t)(s + 1) * D_ + lane * 4) = q;
  }

  // ---- last-block perplexity + scalars (device-scope done counter) ----
  if (tid == 0) {
    __threadfence();
    int old = atomicAdd((int*)acc + 2, 1);
    lastflag = (old == 8 * 64 - 1);
  }
  __syncthreads();
  if (lastflag) {
    int tb = tid >> 5, l32 = tid & 31;        // 8 batches x 32 threads
    float ps = 0.f;
    for (int c = l32; c < C_; c += 32) {
      int h = atomicAdd(&hist[tb * C_ + c], 0);   // coherent read (cross-XCD safe)
      float p = (float)h * (1.0f / (float)S_);
      ps += p * logf(p + 1e-10f);
    }
    #pragma unroll
    for (int off = 1; off < 32; off <<= 1) ps += __shfl_xor(ps, off);
    if (l32 == 0) smP[tb] = expf(-ps);
    __syncthreads();
    if (tid == 0) {
      float P = 0.f;
      #pragma unroll
      for (int i = 0; i < 8; i++) P += smP[i];
      P *= (1.0f / 8.0f);
      float SSE = atomicAdd(&acc[0], 0.0f);
      float L = SSE * (1.0f / 8388608.0f);
      size_t base = (size_t)B_ * SP1_ * D_;
      out[base + 0] = P;
      out[base + 1] = L;
      out[base + 2] = L;
      out[base + 3] = L + 0.25f * L;
    }
  }
}

// ---------------- workspace layout (bytes); esq/hist/acc contiguous (zeroed by K1) ----------------
#define OFF_ESQ   16384u
#define OFF_HIST  (OFF_ESQ + 65536u)
#define OFF_ACC   (OFF_HIST + 65536u)
#define OFF_PROJ  (OFF_ACC + 256u)
#define OFF_ET    (OFF_PROJ + 2097152u)
#define OFF_EMBT  (OFF_ET + 2097152u)
#define OFF_POSB  (OFF_EMBT + 8388608u)
#define OFF_QSQ   (OFF_POSB + 16777216u)

extern "C" void kernel_launch(void* const* d_in, const int* in_sizes, int n_in,
                              void* d_out, int out_size, void* d_ws, size_t ws_size,
                              hipStream_t stream) {
  (void)in_sizes; (void)n_in; (void)out_size; (void)ws_size;
  const float* x    = (const float*)d_in[0];
  const float* E    = (const float*)d_in[1];
  const float* clsw = (const float*)d_in[2];
  const float* clsb = (const float*)d_in[3];
  float* out = (float*)d_out;

  char* ws = (char*)d_ws;
  float* esq  = (float*)(ws + OFF_ESQ);
  int*   hist = (int*)  (ws + OFF_HIST);
  float* acc  = (float*)(ws + OFF_ACC);
  u16*   proj = (u16*)  (ws + OFF_PROJ);
  u16*   ET   = (u16*)  (ws + OFF_ET);
  u16*   embT = (u16*)  (ws + OFF_EMBT);
  u16*   posb = (u16*)  (ws + OFF_POSB);
  float* qsq  = (float*)(ws + OFF_QSQ);

  k_prep<<<K1GRID, 256, 0, stream>>>(x, clsw, clsb, E, posb, qsq, ET, esq, proj, out);
  k_gemm_emb<<<dim3(16, 4, B_), 256, 0, stream>>>(proj, ET, embT, esq);
  k_dist<<<dim3(8, 64), 256, 0, stream>>>(posb, embT, esq, qsq, hist, acc, out);
}